// Round 17
// baseline (75.531 us; speedup 1.0000x reference)
//
#include <hip/hip_runtime.h>
#include <cstdint>

#define NN 512
#define EE 64
#define HIDD 256
#define OUTD 32
#define L2E 1.4426950408889634f

#define AS1 __attribute__((address_space(1)))
#define AS3 __attribute__((address_space(3)))

typedef __bf16 bf16x8 __attribute__((ext_vector_type(8)));
typedef __bf16 bf16x4 __attribute__((ext_vector_type(4)));
typedef float f32x4 __attribute__((ext_vector_type(4)));
typedef float f32x2 __attribute__((ext_vector_type(2)));

// -------- device-global scratch (fully rewritten every call; deterministic) --------
__device__ uint4 g_Ag2[4096];          // bf16 A-frags, gate-scaled; idx = w:3|mh:1|kh:2|lane:6
__device__ float g_biasI[256];         // [e*4 + gate], gate-scaled
__device__ float g_embW[EE*4];         // per-e embed (a,b,bias,0)
__device__ float g_WvT[4096];          // Wv transposed
__device__ float g_Wv2T[4096];         // W_in rows 128-191 transposed
__device__ float g_WoutT[4096];        // W_out transposed
__device__ float g_WoT[EE*OUTD];       // W_o transposed [k][o]
__device__ float g_hs[NN*EE];
__device__ float g_qk[NN*EE];

__device__ __forceinline__ float ex2(float x){ return __builtin_amdgcn_exp2f(x); }
__device__ __forceinline__ float rcp_(float x){ return __builtin_amdgcn_rcpf(x); }

// ---------------- prepK: ONE launch — packing/transposes (blks 0-10) +
// per-row hs/qk chains (blks 11..522) using ONLY raw inputs (no cross-block dep)
__global__ __launch_bounds__(256) void prepK(
    const float* __restrict__ W_ih, const float* __restrict__ b_ih,
    const float* __restrict__ W_hh, const float* __restrict__ b_hh,
    const float* __restrict__ Wq, const float* __restrict__ Wk, const float* __restrict__ Wv,
    const float* __restrict__ W_in, const float* __restrict__ W_hs,
    const float* __restrict__ W_s, const float* __restrict__ b_s,
    const float* __restrict__ W_v, const float* __restrict__ b_v,
    const float* __restrict__ W_out, const float* __restrict__ W_o,
    const float* __restrict__ hidden, const float* __restrict__ b_hs,
    const float* __restrict__ b_in)
{
    __shared__ float shP[64*65];
    const int blk = blockIdx.x, tid = threadIdx.x;
    if (blk < 8) {
        // A-frags: wave w owns e in [8w,8w+8); e = 8w + 2*qq + mh; lane m = 4*qq+gate
#pragma unroll
        for (int ii = 0; ii < 2; ++ii) {
            int idx = blk*512 + ii*256 + tid;
            int w = idx >> 9, mh = (idx >> 8) & 1, kh = (idx >> 6) & 3, lane = idx & 63;
            int m = lane & 15, qq = m >> 2, gate = m & 3;
            int e = 8*w + 2*qq + mh;
            int o = gate*64 + e;
            int kb = kh*32 + (lane >> 4)*8;
            float sc = (gate == 2) ? (-2.f*L2E) : (-L2E);
            bf16x8 vv;
#pragma unroll
            for (int j = 0; j < 8; ++j) {
                int k = kb + j;
                float raw = (k < 64) ? W_ih[o*64 + k] : W_hh[o*64 + (k - 64)];
                vv[j] = (__bf16)(sc * raw);
            }
            g_Ag2[idx] = __builtin_bit_cast(uint4, vv);
        }
    } else if (blk == 8) {
        {
            int e = tid >> 2, gate = tid & 3, o = gate*64 + e;
            float sc = (gate == 2) ? (-2.f*L2E) : (-L2E);
            g_biasI[tid] = sc * (b_ih[o] + b_hh[o]);
        }
        if (tid < 64) {
            int e = tid;
            if (e < 32) {
                g_embW[e*4+0] = W_s[e*2]; g_embW[e*4+1] = W_s[e*2+1]; g_embW[e*4+2] = b_s[e];
            } else {
                g_embW[e*4+0] = 4.f*W_v[(e-32)*2]; g_embW[e*4+1] = 4.f*W_v[(e-32)*2+1]; g_embW[e*4+2] = b_v[e-32];
            }
            g_embW[e*4+3] = 0.f;
        }
    } else if (blk == 9 || blk == 10) {
        auto tr64 = [&](const float* src, float* dst) {
#pragma unroll
            for (int i = 0; i < 16; ++i) {
                int row = i*4 + (tid >> 6), col = tid & 63;
                shP[col*65 + row] = src[row*64 + col];
            }
            __syncthreads();
#pragma unroll
            for (int i = 0; i < 16; ++i) {
                int k = i*4 + (tid >> 6), e = tid & 63;
                dst[k*64 + e] = shP[k*65 + e];
            }
            __syncthreads();
        };
        if (blk == 9) {
            tr64(Wv, g_WvT);
            tr64(W_in + 2*4096, g_Wv2T);        // rows 128-191 (v2)
        } else {
            tr64(W_out, g_WoutT);
            // W_o [32][64] -> g_WoT [64][32]
#pragma unroll
            for (int i = 0; i < 8; ++i) {
                int row = i*4 + (tid >> 6), col = tid & 63;
                shP[col*65 + row] = W_o[row*64 + col];
            }
            __syncthreads();
#pragma unroll
            for (int i = 0; i < 8; ++i) {
                int k = i*8 + (tid >> 5), o = tid & 31;
                g_WoT[k*32 + o] = shP[k*65 + o];
            }
        }
    } else {
        // ---- per-row hs + qk chain from RAW matrices (coalesced) ----
        __shared__ float hid[HIDD];
        __shared__ float vS[64], vT[64];
        __shared__ float part4[4][64];
        const int b = blk - 11;
        const int w = tid >> 6, l = tid & 63;
        hid[tid] = hidden[b*HIDD + tid];
        __syncthreads();
        // hs[e] = sum_k W_hs[e][k] hid[k] + b_hs[e]  (wave-per-e, coalesced rows)
#pragma unroll 1
        for (int i = 0; i < 16; ++i) {
            const int e = w*16 + i;
            float acc = 0.f;
#pragma unroll
            for (int c = 0; c < 4; ++c)
                acc = fmaf(W_hs[e*256 + c*64 + l], hid[c*64 + l], acc);
#pragma unroll
            for (int off = 1; off < 64; off <<= 1) acc += __shfl_xor(acc, off, 64);
            if (l == 0) vS[e] = acc + b_hs[e];
        }
        __syncthreads();
        if (tid < 64) g_hs[b*64 + tid] = vS[tid];
        // x1 = Wq @ hs   (wave-per-row, coalesced rows)
        {
            const float xv = vS[l];
#pragma unroll 1
            for (int i = 0; i < 16; ++i) {
                const int row = w*16 + i;
                float acc = Wq[row*64 + l] * xv;
#pragma unroll
                for (int off = 1; off < 64; off <<= 1) acc += __shfl_xor(acc, off, 64);
                if (l == 0) vT[row] = acc;
            }
        }
        __syncthreads();
        // x2 = Wq2 @ x1 + bq2   (Wq2 = W_in rows 0-63)
        {
            const float xv = vT[l];
#pragma unroll 1
            for (int i = 0; i < 16; ++i) {
                const int row = w*16 + i;
                float acc = W_in[row*64 + l] * xv;
#pragma unroll
                for (int off = 1; off < 64; off <<= 1) acc += __shfl_xor(acc, off, 64);
                if (l == 0) vS[row] = acc + b_in[row];
            }
        }
        __syncthreads();
        // x3 = Wk2^T @ x2   (lanes-on-output, coalesced: M[a*64+l])
        {
            float s = 0.f;
#pragma unroll
            for (int k2 = 0; k2 < 16; ++k2) {
                int kk = w*16 + k2;
                s = fmaf(W_in[4096 + kk*64 + l], vS[kk], s);
            }
            part4[w][l] = s;
        }
        __syncthreads();
        if (tid < 64) vT[tid] = part4[0][tid] + part4[1][tid] + part4[2][tid] + part4[3][tid];
        __syncthreads();
        // qk = (L2E/8) * Wk^T @ x3
        {
            float s = 0.f;
#pragma unroll
            for (int k2 = 0; k2 < 16; ++k2) {
                int kk = w*16 + k2;
                s = fmaf(Wk[kk*64 + l], vT[kk], s);
            }
            part4[w][l] = s;
        }
        __syncthreads();
        if (tid < 64)
            g_qk[b*64 + tid] = (part4[0][tid] + part4[1][tid] + part4[2][tid] + part4[3][tid])
                               * (L2E * 0.125f);
    }
}

// ---------------- row kernel: 512 blocks x 512 thr, full row, 16 tiles of 32,
// ring-3 H/C staged 2 ahead, counted vmcnt(2), obs LDS-resident, 1 barrier/tile
__global__ __launch_bounds__(512, 4) void row_kernel(
    const float* __restrict__ obs1, const float* __restrict__ obs2,
    const float* __restrict__ h0, const float* __restrict__ c0,
    const float* __restrict__ b_in, const float* __restrict__ b_out,
    const float* __restrict__ b_o, float* __restrict__ out)
{
    __shared__ __align__(16) float Hs[3][32*64];          // 24KB, swizzled 256B rows
    __shared__ __align__(16) float Cs[3][32*64];          // 24KB
    __shared__ __align__(16) unsigned short Xe[2][32*64]; // 8KB bf16, swizzled 128B rows
    __shared__ float spart[2][8][32];                     // 2KB
    __shared__ float2 obs1L[NN], obs2L[NN];               // 8KB
    __shared__ float part[8][64];                         // 2KB (epilogue)
    __shared__ float vA[64], vB[64], ctxE[64];

    const int b = blockIdx.x, tid = threadIdx.x;
    const int w = tid >> 6, l = tid & 63;
    const int q = l >> 4, r = l & 15;
    const int ebase0 = 8*w + 2*q;
    const float* h0r = h0 + (size_t)b*NN*EE;
    const float* c0r = c0 + (size_t)b*NN*EE;

    // ---- obs -> LDS (issued FIRST so their waits don't drain stages) ----
    obs2L[tid] = ((const float2*)obs2)[tid];
    obs1L[tid] = ((const float2*)obs1)[tid];

    // ---- register hoists (issued before stages) ----
    uint4 Afr[2][4];
#pragma unroll
    for (int mh = 0; mh < 2; ++mh)
#pragma unroll
        for (int kh = 0; kh < 4; ++kh)
            Afr[mh][kh] = g_Ag2[w*512 + mh*256 + kh*64 + l];
    f32x4 biasv[2];
#pragma unroll
    for (int mh = 0; mh < 2; ++mh) {
        float4 t4 = *(const float4*)(g_biasI + (ebase0 + mh)*4);
        biasv[mh][0]=t4.x; biasv[mh][1]=t4.y; biasv[mh][2]=t4.z; biasv[mh][3]=t4.w;
    }
    float eA[4], eB[4], eC[4];
    {
        const int e0 = (tid & 15)*4;
#pragma unroll
        for (int i = 0; i < 4; ++i) {
            eA[i] = g_embW[(e0+i)*4+0]; eB[i] = g_embW[(e0+i)*4+1]; eC[i] = g_embW[(e0+i)*4+2];
        }
    }
    const f32x2 qkr = *(const f32x2*)(g_qk + b*64 + ebase0);
    const f32x2 hsd = *(const f32x2*)(g_hs + b*64 + ebase0);

    // ---- staging helper ----
    auto stageT = [&](const float* gsrc, float* lbuf) {
        const int row = tid >> 4;                  // 0..31
        const int cb  = (tid & 15) * 16;
        const char* g = (const char*)gsrc + row*256 + (cb ^ ((row & 15) << 4));
        char* lp = (char*)lbuf + tid*16;
        __builtin_amdgcn_global_load_lds((const AS1 void*)g, (AS3 void*)lp, 16, 0, 0);
    };
    // ---- issue stages for tiles 0 and 1 (the ONLY counted in-loop VMEM class) ----
    stageT(h0r, &Hs[0][0]);
    stageT(c0r, &Cs[0][0]);
    stageT(h0r + 32*EE, &Hs[1][0]);
    stageT(c0r + 32*EE, &Cs[1][0]);

    const float ob2x = obs2[b*2], ob2y = obs2[b*2+1];
    const float ob1x = obs1[b*2], ob1y = obs1[b*2+1];
    const float velbx = ob2x - ob1x, velby = ob2y - ob1y;

    auto embedW = [&](int jbg, unsigned short* xe) {
        const int p = tid >> 4;
        const float2 o2 = obs2L[jbg + p];
        const float2 o1 = obs1L[jbg + p];
        const float u0s = o2.x - ob2x, u1s = o2.y - ob2y;
        const float u0v = (o2.x - o1.x) - velbx, u1v = (o2.y - o1.y) - velby;
        const bool sph = ((tid & 15) < 8);
        const float u0 = sph ? u0s : u0v, u1 = sph ? u1s : u1v;
        bf16x4 pk;
#pragma unroll
        for (int i = 0; i < 4; ++i)
            pk[i] = (__bf16)fmaxf(fmaf(eA[i], u0, fmaf(eB[i], u1, eC[i])), 0.f);
        *(bf16x4*)((char*)xe + p*128 + (((tid & 15)*8) ^ ((p & 7) << 4))) = pk;
    };

    // ---- prologue: obs visible -> embed(0) -> tile0 staged (tile1 in flight) ----
    asm volatile("s_waitcnt lgkmcnt(0)" ::: "memory");
    __builtin_amdgcn_s_barrier();
    __builtin_amdgcn_sched_barrier(0);
    embedW(0, &Xe[0][0]);
    asm volatile("s_waitcnt vmcnt(2) lgkmcnt(0)" ::: "memory");
    __builtin_amdgcn_s_barrier();
    __builtin_amdgcn_sched_barrier(0);

    float m_run = -__builtin_inff(), l_run = 0.f;
    float ctxa[2] = {0.f, 0.f};
    float Eev[2][2];
    int hb = 0;

#pragma unroll 1
    for (int t = 0; t < 16; ++t) {
        const int base = t*32;
        const int cx = t & 1;

        // ---- phase 1: softmax(t-1) using spart[cx^1] + Eev registers ----
        if (t > 0) {
            const int c = l & 31;
            const float* spp = &spart[cx ^ 1][0][0];
            float s_p = spp[c];
#pragma unroll
            for (int i = 1; i < 8; ++i) s_p += spp[i*32 + c];
            float tm = s_p;
#pragma unroll
            for (int off = 1; off < 32; off <<= 1) tm = fmaxf(tm, __shfl_xor(tm, off, 64));
            float m_new = fmaxf(m_run, tm);
            float corr = ex2(m_run - m_new);
            float wp = ex2(s_p - m_new);
            l_run = fmaf(l_run, corr, wp);
            m_run = m_new;
            float wn0 = __shfl(wp, r, 64);
            float wn1 = __shfl(wp, 16 + r, 64);
#pragma unroll
            for (int mh = 0; mh < 2; ++mh)
                ctxa[mh] = fmaf(wn1, Eev[mh][1], fmaf(wn0, Eev[mh][0], ctxa[mh]*corr));
        }

        // ---- phase 2: MFMA + LSTM + spart[cx] write (reads ring slot hb) ----
        const float* HsC = &Hs[hb][0];
        const float* CsC = &Cs[hb][0];
        const unsigned short* XeC = &Xe[cx][0];
        f32x2 cpre[2];
#pragma unroll
        for (int nh = 0; nh < 2; ++nh) {
            const int p = 16*nh + r;
            cpre[nh] = *(const f32x2*)((const char*)CsC + p*256 +
                        ((ebase0*4) ^ ((p & 15) << 4)));
        }
        __builtin_amdgcn_s_setprio(1);
        f32x4 acc[2][2];
#pragma unroll
        for (int mh = 0; mh < 2; ++mh)
#pragma unroll
            for (int nh = 0; nh < 2; ++nh) acc[mh][nh] = biasv[mh];
#pragma unroll
        for (int kh = 0; kh < 4; ++kh) {
            const bf16x8 Af0 = __builtin_bit_cast(bf16x8, Afr[0][kh]);
            const bf16x8 Af1 = __builtin_bit_cast(bf16x8, Afr[1][kh]);
#pragma unroll
            for (int nh = 0; nh < 2; ++nh) {
                const int p = 16*nh + r;
                bf16x8 Bf;
                if (kh < 2) {
                    Bf = *(const bf16x8*)((const char*)XeC + p*128 +
                          ((kh*64 + q*16) ^ ((p & 7) << 4)));
                } else {
                    const char* hbp = (const char*)HsC + p*256;
                    const int cbb = (kh - 2)*128 + q*32;
                    const int sw = (p & 15) << 4;
                    f32x4 f0 = *(const f32x4*)(hbp + (cbb ^ sw));
                    f32x4 f1 = *(const f32x4*)(hbp + ((cbb + 16) ^ sw));
                    Bf[0]=(__bf16)f0[0]; Bf[1]=(__bf16)f0[1]; Bf[2]=(__bf16)f0[2]; Bf[3]=(__bf16)f0[3];
                    Bf[4]=(__bf16)f1[0]; Bf[5]=(__bf16)f1[1]; Bf[6]=(__bf16)f1[2]; Bf[7]=(__bf16)f1[3];
                }
                acc[0][nh] = __builtin_amdgcn_mfma_f32_16x16x32_bf16(Af0, Bf, acc[0][nh], 0, 0, 0);
                acc[1][nh] = __builtin_amdgcn_mfma_f32_16x16x32_bf16(Af1, Bf, acc[1][nh], 0, 0, 0);
            }
        }
        float sp[2] = {0.f, 0.f};
#pragma unroll
        for (int nh = 0; nh < 2; ++nh) {
#pragma unroll
            for (int mh = 0; mh < 2; ++mh) {
                f32x4 g4 = acc[mh][nh];           // (yi, yf, yg, yo), pre-scaled
                float ea = ex2(g4[0]);
                float eg = ex2(g4[2]);
                float itg = (1.f - eg) * rcp_((1.f + ea)*(1.f + eg));   // sig(i)*tanh(g)
                float sf = rcp_(1.f + ex2(g4[1]));
                float cn = fmaf(sf, cpre[nh][mh], itg);
                float eo = ex2(g4[3]);
                float ec = ex2(-2.f*L2E*cn);
                float h = (1.f - ec) * rcp_((1.f + eo)*(1.f + ec));     // sig(o)*tanh(cn)
                h = (16*nh + r == b - base) ? hsd[mh] : h;
                Eev[mh][nh] = h;
                sp[nh] = fmaf(qkr[mh], h, sp[nh]);
            }
        }
        __builtin_amdgcn_s_setprio(0);
#pragma unroll
        for (int nh = 0; nh < 2; ++nh) {
            float v = sp[nh];
            v += __shfl_xor(v, 16, 64);
            v += __shfl_xor(v, 32, 64);
            if (q == 0) spart[cx][w][16*nh + r] = v;
        }

        // ---- phase 3: stage(t+2) into ring slot, embed(t+1) ----
        if (t < 14) {
            const int hb2 = (hb == 0) ? 2 : hb - 1;   // (hb+2)%3
            stageT(h0r + (size_t)(t+2)*32*EE, &Hs[hb2][0]);
            stageT(c0r + (size_t)(t+2)*32*EE, &Cs[hb2][0]);
        }
        if (t < 15) embedW(base + 32, &Xe[cx ^ 1][0]);

        // ---- single barrier: spart/Xe visible; tile t+1 staged (counted) ----
        if (t < 14) {
            asm volatile("s_waitcnt vmcnt(2) lgkmcnt(0)" ::: "memory");
        } else {
            asm volatile("s_waitcnt vmcnt(0) lgkmcnt(0)" ::: "memory");
        }
        __builtin_amdgcn_s_barrier();
        __builtin_amdgcn_sched_barrier(0);
        hb = (hb == 2) ? 0 : hb + 1;
    }

    // ---- final softmax (tile 15, spart[1]) ----
    {
        const int c = l & 31;
        const float* spp = &spart[1][0][0];
        float s_p = spp[c];
#pragma unroll
        for (int i = 1; i < 8; ++i) s_p += spp[i*32 + c];
        float tm = s_p;
#pragma unroll
        for (int off = 1; off < 32; off <<= 1) tm = fmaxf(tm, __shfl_xor(tm, off, 64));
        float m_new = fmaxf(m_run, tm);
        float corr = ex2(m_run - m_new);
        float wp = ex2(s_p - m_new);
        l_run = fmaf(l_run, corr, wp);
        m_run = m_new;
        float wn0 = __shfl(wp, r, 64);
        float wn1 = __shfl(wp, 16 + r, 64);
#pragma unroll
        for (int mh = 0; mh < 2; ++mh)
            ctxa[mh] = fmaf(wn1, Eev[mh][1], fmaf(wn0, Eev[mh][0], ctxa[mh]*corr));
    }

    // ---- epilogue: reduce, normalize, chained output projection ----
    float lred = l_run;
    lred += __shfl_xor(lred, 1, 64); lred += __shfl_xor(lred, 2, 64);
    lred += __shfl_xor(lred, 4, 64); lred += __shfl_xor(lred, 8, 64);
    lred += __shfl_xor(lred, 16, 64);
    const float inv = rcp_(lred);
#pragma unroll
    for (int mh = 0; mh < 2; ++mh) {
        float v = ctxa[mh];
        v += __shfl_xor(v, 1, 64); v += __shfl_xor(v, 2, 64);
        v += __shfl_xor(v, 4, 64); v += __shfl_xor(v, 8, 64);
        if (r == 0) ctxE[ebase0 + mh] = v * inv;
    }
    __syncthreads();
    auto matvecG = [&](const float* M, const float* vin, float* vout,
                       const float* bias, float scale) {
        float s = 0.f;
#pragma unroll
        for (int k2 = 0; k2 < 8; ++k2) {
            int kk = w*8 + k2;
            s = fmaf(M[kk*64 + l], vin[kk], s);
        }
        part[w][l] = s;
        __syncthreads();
        if (tid < 64) {
            float v = bias ? bias[tid] : 0.f;
#pragma unroll
            for (int i = 0; i < 8; ++i) v += part[i][tid];
            vout[tid] = v * scale;
        }
        __syncthreads();
    };
    // out = W_o @ (W_out @ (Wv2 @ (Wv @ ctxE) + bv2) + b_out) + b_o
    matvecG(g_WvT,   ctxE, vA, nullptr,    1.f);
    matvecG(g_Wv2T,  vA,   vB, b_in + 128, 1.f);
    matvecG(g_WoutT, vB,   vA, b_out,      1.f);
    {
        if (l < 32) {
            float s = 0.f;
#pragma unroll
            for (int k2 = 0; k2 < 8; ++k2) {
                int kk = w*8 + k2;
                s = fmaf(g_WoT[kk*32 + l], vA[kk], s);
            }
            part[w][l] = s;
        }
        __syncthreads();
        if (tid < 32) {
            float v = b_o[tid];
#pragma unroll
            for (int i = 0; i < 8; ++i) v += part[i][tid];
            out[b*OUTD + tid] = v;
        }
    }
}

extern "C" void kernel_launch(void* const* d_in, const int* in_sizes, int n_in,
                              void* d_out, int out_size, void* d_ws, size_t ws_size,
                              hipStream_t stream) {
    const float* hidden = (const float*)d_in[0];
    const float* obs1   = (const float*)d_in[1];
    const float* obs2   = (const float*)d_in[2];
    const float* h0     = (const float*)d_in[3];
    const float* c0     = (const float*)d_in[4];
    const float* W_s    = (const float*)d_in[5];
    const float* b_s    = (const float*)d_in[6];
    const float* W_v    = (const float*)d_in[7];
    const float* b_v    = (const float*)d_in[8];
    const float* W_hs   = (const float*)d_in[9];
    const float* b_hs   = (const float*)d_in[10];
    const float* W_ih   = (const float*)d_in[11];
    const float* b_ih   = (const float*)d_in[12];
    const float* W_hh   = (const float*)d_in[13];
    const float* b_hh   = (const float*)d_in[14];
    const float* Wq     = (const float*)d_in[15];
    const float* Wk     = (const float*)d_in[16];
    const float* Wv     = (const float*)d_in[17];
    const float* W_in   = (const float*)d_in[18];
    const float* b_in   = (const float*)d_in[19];
    const float* W_out  = (const float*)d_in[20];
    const float* b_out  = (const float*)d_in[21];
    const float* W_o    = (const float*)d_in[22];
    const float* b_o    = (const float*)d_in[23];

    prepK<<<dim3(11 + NN), dim3(256), 0, stream>>>(
        W_ih, b_ih, W_hh, b_hh, Wq, Wk, Wv, W_in, W_hs, W_s, b_s, W_v, b_v,
        W_out, W_o, hidden, b_hs, b_in);
    row_kernel<<<dim3(NN), dim3(512), 0, stream>>>(
        obs1, obs2, h0, c0, b_in, b_out, b_o, (float*)d_out);
}

// Round 18
// 59.501 us; speedup vs baseline: 1.2694x; 1.2694x over previous
//
#include <hip/hip_runtime.h>
#include <cstdint>

#define NN 512
#define EE 64
#define HIDD 256
#define OUTD 32
#define L2E 1.4426950408889634f

#define AS1 __attribute__((address_space(1)))
#define AS3 __attribute__((address_space(3)))

typedef __bf16 bf16x8 __attribute__((ext_vector_type(8)));
typedef __bf16 bf16x4 __attribute__((ext_vector_type(4)));
typedef float f32x4 __attribute__((ext_vector_type(4)));
typedef float f32x2 __attribute__((ext_vector_type(2)));

// -------- device-global scratch (fully rewritten every call; deterministic) --------
__device__ float g_WhsT[HIDD*EE];      // W_hs transposed [k][e]
__device__ uint4 g_Ag2[4096];          // bf16 A-frags, gate-scaled; idx = w:3|mh:1|kh:2|lane:6
__device__ float g_biasI[256];         // [e*4 + gate], gate-scaled
__device__ float g_embW[EE*4];         // per-e embed (a,b,bias,0)
__device__ float g_WqT[4096];          // Wq transposed
__device__ float g_Wq2T[4096];         // W_in rows 0-63 transposed
__device__ float g_WvT[4096];          // Wv transposed
__device__ float g_Wv2T[4096];         // W_in rows 128-191 transposed
__device__ float g_WoutT[4096];        // W_out transposed
__device__ float g_WoT[EE*OUTD];       // W_o transposed [k][o]
__device__ float g_hs[NN*EE];
__device__ float g_qk[NN*EE];

__device__ __forceinline__ float ex2(float x){ return __builtin_amdgcn_exp2f(x); }
__device__ __forceinline__ float rcp_(float x){ return __builtin_amdgcn_rcpf(x); }

// ---------------- prepA: packing + transposes ONLY (13 blocks, no matmuls) --
__global__ __launch_bounds__(256) void prepA(
    const float* __restrict__ W_ih, const float* __restrict__ b_ih,
    const float* __restrict__ W_hh, const float* __restrict__ b_hh,
    const float* __restrict__ Wq, const float* __restrict__ Wv,
    const float* __restrict__ W_in, const float* __restrict__ W_hs,
    const float* __restrict__ W_s, const float* __restrict__ b_s,
    const float* __restrict__ W_v, const float* __restrict__ b_v,
    const float* __restrict__ W_out, const float* __restrict__ W_o)
{
    __shared__ float shP[64*65];
    const int blk = blockIdx.x, tid = threadIdx.x;
    if (blk < 8) {
        // A-frags: wave w owns e in [8w,8w+8); e = 8w + 2*qq + mh; lane m = 4*qq+gate
#pragma unroll
        for (int ii = 0; ii < 2; ++ii) {
            int idx = blk*512 + ii*256 + tid;
            int w = idx >> 9, mh = (idx >> 8) & 1, kh = (idx >> 6) & 3, lane = idx & 63;
            int m = lane & 15, qq = m >> 2, gate = m & 3;
            int e = 8*w + 2*qq + mh;
            int o = gate*64 + e;
            int kb = kh*32 + (lane >> 4)*8;
            float sc = (gate == 2) ? (-2.f*L2E) : (-L2E);
            bf16x8 vv;
#pragma unroll
            for (int j = 0; j < 8; ++j) {
                int k = kb + j;
                float raw = (k < 64) ? W_ih[o*64 + k] : W_hh[o*64 + (k - 64)];
                vv[j] = (__bf16)(sc * raw);
            }
            g_Ag2[idx] = __builtin_bit_cast(uint4, vv);
        }
    } else if (blk == 8) {
        {
            int e = tid >> 2, gate = tid & 3, o = gate*64 + e;
            float sc = (gate == 2) ? (-2.f*L2E) : (-L2E);
            g_biasI[tid] = sc * (b_ih[o] + b_hh[o]);
        }
        if (tid < 64) {
            int e = tid;
            if (e < 32) {
                g_embW[e*4+0] = W_s[e*2]; g_embW[e*4+1] = W_s[e*2+1]; g_embW[e*4+2] = b_s[e];
            } else {
                g_embW[e*4+0] = 4.f*W_v[(e-32)*2]; g_embW[e*4+1] = 4.f*W_v[(e-32)*2+1]; g_embW[e*4+2] = b_v[e-32];
            }
            g_embW[e*4+3] = 0.f;
        }
    } else if (blk == 9) {
        // LDS-tiled transpose W_hs [64][256] -> g_WhsT [256][64]
        for (int kt = 0; kt < 4; ++kt) {
            __syncthreads();
#pragma unroll
            for (int i = 0; i < 16; ++i) {
                int row = i*4 + (tid >> 6), col = tid & 63;
                shP[col*65 + row] = W_hs[row*256 + kt*64 + col];
            }
            __syncthreads();
#pragma unroll
            for (int i = 0; i < 16; ++i) {
                int krow = i*4 + (tid >> 6), e = tid & 63;
                g_WhsT[(kt*64 + krow)*64 + e] = shP[krow*65 + e];
            }
        }
    } else {
        auto tr64 = [&](const float* src, float* dst) {
#pragma unroll
            for (int i = 0; i < 16; ++i) {
                int row = i*4 + (tid >> 6), col = tid & 63;
                shP[col*65 + row] = src[row*64 + col];
            }
            __syncthreads();
#pragma unroll
            for (int i = 0; i < 16; ++i) {
                int k = i*4 + (tid >> 6), e = tid & 63;
                dst[k*64 + e] = shP[k*65 + e];
            }
            __syncthreads();
        };
        if (blk == 10) {
            tr64(Wq, g_WqT);
            tr64(W_in, g_Wq2T);                 // rows 0-63 (q2)
        } else if (blk == 11) {
            tr64(Wv, g_WvT);
            tr64(W_in + 2*4096, g_Wv2T);        // rows 128-191 (v2)
        } else {
            tr64(W_out, g_WoutT);
            // W_o [32][64] -> g_WoT [64][32]
#pragma unroll
            for (int i = 0; i < 8; ++i) {
                int row = i*4 + (tid >> 6), col = tid & 63;
                shP[col*65 + row] = W_o[row*64 + col];
            }
            __syncthreads();
#pragma unroll
            for (int i = 0; i < 8; ++i) {
                int k = i*8 + (tid >> 5), o = tid & 31;
                g_WoT[k*32 + o] = shP[k*65 + o];
            }
        }
    }
}

// ---------------- prepB: per-row hs + qk chain (512 blocks x 256) -----------
__global__ __launch_bounds__(256) void prepB(
    const float* __restrict__ hidden, const float* __restrict__ b_hs,
    const float* __restrict__ W_in, const float* __restrict__ Wk,
    const float* __restrict__ b_in)
{
    __shared__ float hid[HIDD];
    __shared__ float part4[4][64];
    __shared__ float v0[64], v1[64];
    const int b = blockIdx.x, tid = threadIdx.x;
    const int e = tid & 63, kq = tid >> 6;
    hid[tid] = hidden[b*HIDD + tid];
    __syncthreads();
    {
        float s = 0.f;
#pragma unroll 8
        for (int k2 = 0; k2 < 64; ++k2) {
            int kk = kq*64 + k2;
            s = fmaf(g_WhsT[kk*64 + e], hid[kk], s);
        }
        part4[kq][e] = s;
    }
    __syncthreads();
    if (tid < 64) {
        float v = part4[0][tid] + part4[1][tid] + part4[2][tid] + part4[3][tid] + b_hs[tid];
        g_hs[b*64 + tid] = v;
        v0[tid] = v;
    }
    __syncthreads();
    auto mv = [&](const float* M, const float* vin, float* vout,
                  const float* bias, float scale) {
        float s = 0.f;
#pragma unroll
        for (int k2 = 0; k2 < 16; ++k2) {
            int kk = kq*16 + k2;
            s = fmaf(M[kk*64 + e], vin[kk], s);
        }
        part4[kq][e] = s;
        __syncthreads();
        if (tid < 64) {
            float v = bias ? bias[tid] : 0.f;
            v += part4[0][tid] + part4[1][tid] + part4[2][tid] + part4[3][tid];
            vout[tid] = v * scale;
        }
        __syncthreads();
    };
    // qk = (L2E/8) * Wk^T @ Wk2^T @ (Wq2 @ (Wq @ hs) + bq2)
    mv(g_WqT,        v0, v1, nullptr, 1.f);
    mv(g_Wq2T,       v1, v0, b_in,    1.f);
    mv(W_in + 4096,  v0, v1, nullptr, 1.f);
    mv(Wk,           v1, g_qk + b*64, nullptr, L2E*0.125f);
}

// ---------------- row kernel: 512 blocks x 512 thr, full row, 16 tiles of 32,
// ring-3 H/C staged 2 ahead, counted vmcnt(2), obs LDS-resident, 1 barrier/tile
__global__ __launch_bounds__(512, 4) void row_kernel(
    const float* __restrict__ obs1, const float* __restrict__ obs2,
    const float* __restrict__ h0, const float* __restrict__ c0,
    const float* __restrict__ b_in, const float* __restrict__ b_out,
    const float* __restrict__ b_o, float* __restrict__ out)
{
    __shared__ __align__(16) float Hs[3][32*64];          // 24KB, swizzled 256B rows
    __shared__ __align__(16) float Cs[3][32*64];          // 24KB
    __shared__ __align__(16) unsigned short Xe[2][32*64]; // 8KB bf16, swizzled 128B rows
    __shared__ float spart[2][8][32];                     // 2KB
    __shared__ float2 obs1L[NN], obs2L[NN];               // 8KB
    __shared__ float part[8][64];                         // 2KB (epilogue)
    __shared__ float vA[64], vB[64], ctxE[64];

    const int b = blockIdx.x, tid = threadIdx.x;
    const int w = tid >> 6, l = tid & 63;
    const int q = l >> 4, r = l & 15;
    const int ebase0 = 8*w + 2*q;
    const float* h0r = h0 + (size_t)b*NN*EE;
    const float* c0r = c0 + (size_t)b*NN*EE;

    // ---- obs -> LDS (loads issued FIRST so their waits don't drain stages) ----
    obs2L[tid] = ((const float2*)obs2)[tid];
    obs1L[tid] = ((const float2*)obs1)[tid];

    // ---- register hoists (issued before stages) ----
    uint4 Afr[2][4];
#pragma unroll
    for (int mh = 0; mh < 2; ++mh)
#pragma unroll
        for (int kh = 0; kh < 4; ++kh)
            Afr[mh][kh] = g_Ag2[w*512 + mh*256 + kh*64 + l];
    f32x4 biasv[2];
#pragma unroll
    for (int mh = 0; mh < 2; ++mh) {
        float4 t4 = *(const float4*)(g_biasI + (ebase0 + mh)*4);
        biasv[mh][0]=t4.x; biasv[mh][1]=t4.y; biasv[mh][2]=t4.z; biasv[mh][3]=t4.w;
    }
    float eA[4], eB[4], eC[4];
    {
        const int e0 = (tid & 15)*4;
#pragma unroll
        for (int i = 0; i < 4; ++i) {
            eA[i] = g_embW[(e0+i)*4+0]; eB[i] = g_embW[(e0+i)*4+1]; eC[i] = g_embW[(e0+i)*4+2];
        }
    }
    const f32x2 qkr = *(const f32x2*)(g_qk + b*64 + ebase0);
    const f32x2 hsd = *(const f32x2*)(g_hs + b*64 + ebase0);

    // ---- staging helper ----
    auto stageT = [&](const float* gsrc, float* lbuf) {
        const int row = tid >> 4;                  // 0..31
        const int cb  = (tid & 15) * 16;
        const char* g = (const char*)gsrc + row*256 + (cb ^ ((row & 15) << 4));
        char* lp = (char*)lbuf + tid*16;
        __builtin_amdgcn_global_load_lds((const AS1 void*)g, (AS3 void*)lp, 16, 0, 0);
    };
    // ---- issue stages for tiles 0 and 1 (the ONLY counted in-loop VMEM class) ----
    stageT(h0r, &Hs[0][0]);
    stageT(c0r, &Cs[0][0]);
    stageT(h0r + 32*EE, &Hs[1][0]);
    stageT(c0r + 32*EE, &Cs[1][0]);

    const float ob2x = obs2[b*2], ob2y = obs2[b*2+1];
    const float ob1x = obs1[b*2], ob1y = obs1[b*2+1];
    const float velbx = ob2x - ob1x, velby = ob2y - ob1y;

    auto embedW = [&](int jbg, unsigned short* xe) {
        const int p = tid >> 4;
        const float2 o2 = obs2L[jbg + p];
        const float2 o1 = obs1L[jbg + p];
        const float u0s = o2.x - ob2x, u1s = o2.y - ob2y;
        const float u0v = (o2.x - o1.x) - velbx, u1v = (o2.y - o1.y) - velby;
        const bool sph = ((tid & 15) < 8);
        const float u0 = sph ? u0s : u0v, u1 = sph ? u1s : u1v;
        bf16x4 pk;
#pragma unroll
        for (int i = 0; i < 4; ++i)
            pk[i] = (__bf16)fmaxf(fmaf(eA[i], u0, fmaf(eB[i], u1, eC[i])), 0.f);
        *(bf16x4*)((char*)xe + p*128 + (((tid & 15)*8) ^ ((p & 7) << 4))) = pk;
    };

    // ---- prologue: obs visible -> embed(0) -> tile0 staged (tile1 in flight) ----
    asm volatile("s_waitcnt lgkmcnt(0)" ::: "memory");
    __builtin_amdgcn_s_barrier();
    __builtin_amdgcn_sched_barrier(0);
    embedW(0, &Xe[0][0]);
    asm volatile("s_waitcnt vmcnt(2) lgkmcnt(0)" ::: "memory");
    __builtin_amdgcn_s_barrier();
    __builtin_amdgcn_sched_barrier(0);

    float m_run = -__builtin_inff(), l_run = 0.f;
    float ctxa[2] = {0.f, 0.f};
    float Eev[2][2];
    int hb = 0;

#pragma unroll 1
    for (int t = 0; t < 16; ++t) {
        const int base = t*32;
        const int cx = t & 1;

        // ---- phase 1: softmax(t-1) using spart[cx^1] + Eev registers ----
        if (t > 0) {
            const int c = l & 31;
            const float* spp = &spart[cx ^ 1][0][0];
            float s_p = spp[c];
#pragma unroll
            for (int i = 1; i < 8; ++i) s_p += spp[i*32 + c];
            float tm = s_p;
#pragma unroll
            for (int off = 1; off < 32; off <<= 1) tm = fmaxf(tm, __shfl_xor(tm, off, 64));
            float m_new = fmaxf(m_run, tm);
            float corr = ex2(m_run - m_new);
            float wp = ex2(s_p - m_new);
            l_run = fmaf(l_run, corr, wp);
            m_run = m_new;
            float wn0 = __shfl(wp, r, 64);
            float wn1 = __shfl(wp, 16 + r, 64);
#pragma unroll
            for (int mh = 0; mh < 2; ++mh)
                ctxa[mh] = fmaf(wn1, Eev[mh][1], fmaf(wn0, Eev[mh][0], ctxa[mh]*corr));
        }

        // ---- phase 2: MFMA + LSTM + spart[cx] write (reads ring slot hb) ----
        const float* HsC = &Hs[hb][0];
        const float* CsC = &Cs[hb][0];
        const unsigned short* XeC = &Xe[cx][0];
        f32x2 cpre[2];
#pragma unroll
        for (int nh = 0; nh < 2; ++nh) {
            const int p = 16*nh + r;
            cpre[nh] = *(const f32x2*)((const char*)CsC + p*256 +
                        ((ebase0*4) ^ ((p & 15) << 4)));
        }
        __builtin_amdgcn_s_setprio(1);
        f32x4 acc[2][2];
#pragma unroll
        for (int mh = 0; mh < 2; ++mh)
#pragma unroll
            for (int nh = 0; nh < 2; ++nh) acc[mh][nh] = biasv[mh];
#pragma unroll
        for (int kh = 0; kh < 4; ++kh) {
            const bf16x8 Af0 = __builtin_bit_cast(bf16x8, Afr[0][kh]);
            const bf16x8 Af1 = __builtin_bit_cast(bf16x8, Afr[1][kh]);
#pragma unroll
            for (int nh = 0; nh < 2; ++nh) {
                const int p = 16*nh + r;
                bf16x8 Bf;
                if (kh < 2) {
                    Bf = *(const bf16x8*)((const char*)XeC + p*128 +
                          ((kh*64 + q*16) ^ ((p & 7) << 4)));
                } else {
                    const char* hbp = (const char*)HsC + p*256;
                    const int cbb = (kh - 2)*128 + q*32;
                    const int sw = (p & 15) << 4;
                    f32x4 f0 = *(const f32x4*)(hbp + (cbb ^ sw));
                    f32x4 f1 = *(const f32x4*)(hbp + ((cbb + 16) ^ sw));
                    Bf[0]=(__bf16)f0[0]; Bf[1]=(__bf16)f0[1]; Bf[2]=(__bf16)f0[2]; Bf[3]=(__bf16)f0[3];
                    Bf[4]=(__bf16)f1[0]; Bf[5]=(__bf16)f1[1]; Bf[6]=(__bf16)f1[2]; Bf[7]=(__bf16)f1[3];
                }
                acc[0][nh] = __builtin_amdgcn_mfma_f32_16x16x32_bf16(Af0, Bf, acc[0][nh], 0, 0, 0);
                acc[1][nh] = __builtin_amdgcn_mfma_f32_16x16x32_bf16(Af1, Bf, acc[1][nh], 0, 0, 0);
            }
        }
        float sp[2] = {0.f, 0.f};
#pragma unroll
        for (int nh = 0; nh < 2; ++nh) {
#pragma unroll
            for (int mh = 0; mh < 2; ++mh) {
                f32x4 g4 = acc[mh][nh];           // (yi, yf, yg, yo), pre-scaled
                float ea = ex2(g4[0]);
                float eg = ex2(g4[2]);
                float itg = (1.f - eg) * rcp_((1.f + ea)*(1.f + eg));   // sig(i)*tanh(g)
                float sf = rcp_(1.f + ex2(g4[1]));
                float cn = fmaf(sf, cpre[nh][mh], itg);
                float eo = ex2(g4[3]);
                float ec = ex2(-2.f*L2E*cn);
                float h = (1.f - ec) * rcp_((1.f + eo)*(1.f + ec));     // sig(o)*tanh(cn)
                h = (16*nh + r == b - base) ? hsd[mh] : h;
                Eev[mh][nh] = h;
                sp[nh] = fmaf(qkr[mh], h, sp[nh]);
            }
        }
        __builtin_amdgcn_s_setprio(0);
#pragma unroll
        for (int nh = 0; nh < 2; ++nh) {
            float v = sp[nh];
            v += __shfl_xor(v, 16, 64);
            v += __shfl_xor(v, 32, 64);
            if (q == 0) spart[cx][w][16*nh + r] = v;
        }

        // ---- phase 3: stage(t+2) into ring slot, embed(t+1) ----
        if (t < 14) {
            const int hb2 = (hb == 0) ? 2 : hb - 1;   // (hb+2)%3
            stageT(h0r + (size_t)(t+2)*32*EE, &Hs[hb2][0]);
            stageT(c0r + (size_t)(t+2)*32*EE, &Cs[hb2][0]);
        }
        if (t < 15) embedW(base + 32, &Xe[cx ^ 1][0]);

        // ---- single barrier: spart/Xe visible; tile t+1 staged (counted) ----
        if (t < 14) {
            asm volatile("s_waitcnt vmcnt(2) lgkmcnt(0)" ::: "memory");
        } else {
            asm volatile("s_waitcnt vmcnt(0) lgkmcnt(0)" ::: "memory");
        }
        __builtin_amdgcn_s_barrier();
        __builtin_amdgcn_sched_barrier(0);
        hb = (hb == 2) ? 0 : hb + 1;
    }

    // ---- final softmax (tile 15, spart[1]) ----
    {
        const int c = l & 31;
        const float* spp = &spart[1][0][0];
        float s_p = spp[c];
#pragma unroll
        for (int i = 1; i < 8; ++i) s_p += spp[i*32 + c];
        float tm = s_p;
#pragma unroll
        for (int off = 1; off < 32; off <<= 1) tm = fmaxf(tm, __shfl_xor(tm, off, 64));
        float m_new = fmaxf(m_run, tm);
        float corr = ex2(m_run - m_new);
        float wp = ex2(s_p - m_new);
        l_run = fmaf(l_run, corr, wp);
        m_run = m_new;
        float wn0 = __shfl(wp, r, 64);
        float wn1 = __shfl(wp, 16 + r, 64);
#pragma unroll
        for (int mh = 0; mh < 2; ++mh)
            ctxa[mh] = fmaf(wn1, Eev[mh][1], fmaf(wn0, Eev[mh][0], ctxa[mh]*corr));
    }

    // ---- epilogue: reduce, normalize, chained output projection ----
    float lred = l_run;
    lred += __shfl_xor(lred, 1, 64); lred += __shfl_xor(lred, 2, 64);
    lred += __shfl_xor(lred, 4, 64); lred += __shfl_xor(lred, 8, 64);
    lred += __shfl_xor(lred, 16, 64);
    const float inv = rcp_(lred);
#pragma unroll
    for (int mh = 0; mh < 2; ++mh) {
        float v = ctxa[mh];
        v += __shfl_xor(v, 1, 64); v += __shfl_xor(v, 2, 64);
        v += __shfl_xor(v, 4, 64); v += __shfl_xor(v, 8, 64);
        if (r == 0) ctxE[ebase0 + mh] = v * inv;
    }
    __syncthreads();
    auto matvecG = [&](const float* M, const float* vin, float* vout,
                       const float* bias, float scale) {
        float s = 0.f;
#pragma unroll
        for (int k2 = 0; k2 < 8; ++k2) {
            int kk = w*8 + k2;
            s = fmaf(M[kk*64 + l], vin[kk], s);
        }
        part[w][l] = s;
        __syncthreads();
        if (tid < 64) {
            float v = bias ? bias[tid] : 0.f;
#pragma unroll
            for (int i = 0; i < 8; ++i) v += part[i][tid];
            vout[tid] = v * scale;
        }
        __syncthreads();
    };
    // out = W_o @ (W_out @ (Wv2 @ (Wv @ ctxE) + bv2) + b_out) + b_o
    matvecG(g_WvT,   ctxE, vA, nullptr,    1.f);
    matvecG(g_Wv2T,  vA,   vB, b_in + 128, 1.f);
    matvecG(g_WoutT, vB,   vA, b_out,      1.f);
    {
        if (l < 32) {
            float s = 0.f;
#pragma unroll
            for (int k2 = 0; k2 < 8; ++k2) {
                int kk = w*8 + k2;
                s = fmaf(g_WoT[kk*32 + l], vA[kk], s);
            }
            part[w][l] = s;
        }
        __syncthreads();
        if (tid < 32) {
            float v = b_o[tid];
#pragma unroll
            for (int i = 0; i < 8; ++i) v += part[i][tid];
            out[b*OUTD + tid] = v;
        }
    }
}

extern "C" void kernel_launch(void* const* d_in, const int* in_sizes, int n_in,
                              void* d_out, int out_size, void* d_ws, size_t ws_size,
                              hipStream_t stream) {
    const float* hidden = (const float*)d_in[0];
    const float* obs1   = (const float*)d_in[1];
    const float* obs2   = (const float*)d_in[2];
    const float* h0     = (const float*)d_in[3];
    const float* c0     = (const float*)d_in[4];
    const float* W_s    = (const float*)d_in[5];
    const float* b_s    = (const float*)d_in[6];
    const float* W_v    = (const float*)d_in[7];
    const float* b_v    = (const float*)d_in[8];
    const float* W_hs   = (const float*)d_in[9];
    const float* b_hs   = (const float*)d_in[10];
    const float* W_ih   = (const float*)d_in[11];
    const float* b_ih   = (const float*)d_in[12];
    const float* W_hh   = (const float*)d_in[13];
    const float* b_hh   = (const float*)d_in[14];
    const float* Wq     = (const float*)d_in[15];
    const float* Wk     = (const float*)d_in[16];
    const float* Wv     = (const float*)d_in[17];
    const float* W_in   = (const float*)d_in[18];
    const float* b_in   = (const float*)d_in[19];
    const float* W_out  = (const float*)d_in[20];
    const float* b_out  = (const float*)d_in[21];
    const float* W_o    = (const float*)d_in[22];
    const float* b_o    = (const float*)d_in[23];

    prepA<<<dim3(13), dim3(256), 0, stream>>>(
        W_ih, b_ih, W_hh, b_hh, Wq, Wv, W_in, W_hs, W_s, b_s, W_v, b_v, W_out, W_o);
    prepB<<<dim3(NN), dim3(256), 0, stream>>>(hidden, b_hs, W_in, Wk, b_in);
    row_kernel<<<dim3(NN), dim3(512), 0, stream>>>(
        obs1, obs2, h0, c0, b_in, b_out, b_o, (float*)d_out);
}